// Round 6
// baseline (711.042 us; speedup 1.0000x reference)
//
#include <hip/hip_runtime.h>
#include <hip/hip_bf16.h>
#include <math.h>

typedef __bf16 bf16;
typedef __bf16 bf16x4 __attribute__((ext_vector_type(4)));
typedef __bf16 bf16x8 __attribute__((ext_vector_type(8)));
typedef float f32x4 __attribute__((ext_vector_type(4)));
typedef unsigned int u32x4 __attribute__((ext_vector_type(4)));

#define NHEADS 6
#define CDIM 192
#define IMG 56
#define NTOK 49
#define SHIFTV 3
#define XSTR 200   // padded row stride (bf16) for BufA: 400 B
#define VSTR 72    // padded stride for VT: 144 B
#define LOG2E 1.4426950408889634f
#define SCALE 0.17677669529663687f

static __device__ __forceinline__ unsigned pack2bf(float lo, float hi) {
    unsigned short a = __builtin_bit_cast(unsigned short, (bf16)lo);
    unsigned short b = __builtin_bit_cast(unsigned short, (bf16)hi);
    return (unsigned)a | ((unsigned)b << 16);
}

// ---- prep: weight transpose->bf16 + fused (bias+mask)*log2e table ----
// biasG[class c][head h][i 64][j 64], c = (wy==7)*2 + (wx==7)
__global__ void prep_weights(const float* __restrict__ w_qkv, const float* __restrict__ w_proj,
                             const float* __restrict__ rel_table,
                             bf16* __restrict__ wqkvT, bf16* __restrict__ wprojT,
                             bf16* __restrict__ biasG) {
    int i = blockIdx.x * 256 + threadIdx.x;
    if (i < 576 * 192) {
        int n = i / 192, k = i % 192;
        wqkvT[i] = (bf16)w_qkv[k * 576 + n];
    }
    if (i < 192 * 192) {
        int n = i / 192, k = i % 192;
        wprojT[i] = (bf16)w_proj[k * 192 + n];
    }
    if (i < 24 * 64 * 64) {
        int j = i & 63, ii = (i >> 6) & 63, t = i >> 12;
        int h = t % 6, c = t / 6;
        float val = -100.f;
        if (ii < 49 && j < 49) {
            int iy = ii / 7, ix = ii % 7, jy = j / 7, jx = j % 7;
            int rp = (iy - jy + 6) * 13 + (ix - jx + 6);
            bool ym = !(c & 2) || ((iy < 4) == (jy < 4));
            bool xm = !(c & 1) || ((ix < 4) == (jx < 4));
            val = rel_table[rp * 6 + h] + ((ym && xm) ? 0.f : -100.f);
        }
        biasG[i] = (bf16)(val * LOG2E);
    }
}

__global__ __launch_bounds__(512, 6) void swin_block(
    const float* __restrict__ x, const float* __restrict__ gamma, const float* __restrict__ beta,
    const bf16* __restrict__ wqkvT, const float* __restrict__ b_qkv,
    const bf16* __restrict__ biasG, const bf16* __restrict__ wprojT,
    const float* __restrict__ b_proj, float* __restrict__ out)
{
    __shared__ __align__(16) bf16 BufA[64 * XSTR];     // X (ph0-1) -> K (ph1-2) -> O (ph2-3)
    __shared__ __align__(16) bf16 VTs[CDIM * VSTR];    // V transposed: [channel][token]
    // total 53248 B -> 3 blocks/CU

    const int blk  = blockIdx.x;
    const int bimg = blk >> 6;
    const int wy   = (blk >> 3) & 7;
    const int wx   = blk & 7;
    const int tid  = threadIdx.x;
    const int wave = tid >> 6;   // 0..7
    const int lane = tid & 63;
    const int lr   = lane & 15;
    const int lq   = lane >> 4;

    // wave roles: phase1 K/V: half h0, col-group cg; phase2: row-tile m2, head-group hg
    const int h0     = wave & 1;
    const int cg     = (wave >> 1) & 3;
    const int mm_sel = (wave >> 1) & 1;
    const int m2     = 2 * h0 + mm_sel;      // bijective over low 2 bits of wave
    const int hg     = wave >> 2;

    // ---- phase 0: shifted-window load + LayerNorm -> BufA (bf16), rows 49..63 zero ----
    {
        const float g0 = gamma[lane], g1 = gamma[lane + 64], g2 = gamma[lane + 128];
        const float b0 = beta[lane],  b1 = beta[lane + 64],  b2 = beta[lane + 128];
        for (int t = wave; t < 64; t += 8) {
            if (t < NTOK) {
                int ty = t / 7, tx = t % 7;
                int oy = wy * 7 + ty + SHIFTV; if (oy >= IMG) oy -= IMG;
                int ox = wx * 7 + tx + SHIFTV; if (ox >= IMG) ox -= IMG;
                const float* xp = x + (((size_t)bimg * IMG + oy) * IMG + ox) * CDIM;
                float v0 = xp[lane], v1 = xp[lane + 64], v2 = xp[lane + 128];
                float s = v0 + v1 + v2, ss = v0 * v0 + v1 * v1 + v2 * v2;
                #pragma unroll
                for (int off = 32; off; off >>= 1) { s += __shfl_xor(s, off); ss += __shfl_xor(ss, off); }
                float mu  = s * (1.f / 192.f);
                float var = ss * (1.f / 192.f) - mu * mu;
                float rs  = rsqrtf(var + 1e-5f);
                BufA[t * XSTR + lane      ] = (bf16)((v0 - mu) * rs * g0 + b0);
                BufA[t * XSTR + lane + 64 ] = (bf16)((v1 - mu) * rs * g1 + b1);
                BufA[t * XSTR + lane + 128] = (bf16)((v2 - mu) * rs * g2 + b2);
            } else {
                BufA[t * XSTR + lane      ] = (bf16)0.f;
                BufA[t * XSTR + lane + 64 ] = (bf16)0.f;
                BufA[t * XSTR + lane + 128] = (bf16)0.f;
            }
        }
    }
    __syncthreads();

    // ---- phase 1: cache X; K -> BufA (over X), V^T -> VTs; then Q on-the-fly -> registers ----
    bf16x8 qf[3];      // per-head Q B-fragments (built below)
    {
        bf16x8 afrag[2][6];
        #pragma unroll
        for (int mm = 0; mm < 2; ++mm)
            #pragma unroll
            for (int k = 0; k < 6; ++k)
                afrag[mm][k] = *(const bf16x8*)&BufA[(32 * h0 + 16 * mm + lr) * XSTR + k * 32 + lq * 8];
        __syncthreads();   // all waves cached X before K overwrites BufA

        // K (t=0..2 -> ntkv 0..11) then V (t=3..5 -> ntkv 12..23)
        for (int t = 0; t < 6; ++t) {
            const int ntkv = cg + 4 * t;
            const bf16* wp = wqkvT + (size_t)((12 + ntkv) * 16 + lr) * CDIM + lq * 8;
            bf16x8 bfrag[6];
            #pragma unroll
            for (int k = 0; k < 6; ++k) bfrag[k] = *(const bf16x8*)(wp + k * 32);
            f32x4 acc[2];
            acc[0] = f32x4{0.f, 0.f, 0.f, 0.f}; acc[1] = f32x4{0.f, 0.f, 0.f, 0.f};
            if (ntkv >= 12) {
                // V: unswapped -> D: channel = (ntkv-12)*16+lr, token packed 4lq+r
                #pragma unroll
                for (int k = 0; k < 6; ++k)
                    #pragma unroll
                    for (int mm = 0; mm < 2; ++mm)
                        acc[mm] = __builtin_amdgcn_mfma_f32_16x16x32_bf16(afrag[mm][k], bfrag[k], acc[mm], 0, 0, 0);
                const int cc   = (ntkv - 12) * 16 + lr;
                const float bb = b_qkv[384 + cc];
                #pragma unroll
                for (int mm = 0; mm < 2; ++mm) {
                    bf16x4 v4;
                    #pragma unroll
                    for (int r = 0; r < 4; ++r) v4[r] = (bf16)(acc[mm][r] + bb);
                    *(bf16x4*)&VTs[cc * VSTR + 32 * h0 + 16 * mm + 4 * lq] = v4;
                }
            } else {
                // K: swapped -> D: token = 32h0+16mm+lr, channel packed ntkv*16+4lq+r
                #pragma unroll
                for (int k = 0; k < 6; ++k)
                    #pragma unroll
                    for (int mm = 0; mm < 2; ++mm)
                        acc[mm] = __builtin_amdgcn_mfma_f32_16x16x32_bf16(bfrag[k], afrag[mm][k], acc[mm], 0, 0, 0);
                const int ccl = ntkv * 16 + 4 * lq;
                const f32x4 bq4 = *(const f32x4*)&b_qkv[192 + ccl];
                #pragma unroll
                for (int mm = 0; mm < 2; ++mm) {
                    bf16x4 v4;
                    #pragma unroll
                    for (int r = 0; r < 4; ++r) v4[r] = (bf16)(acc[mm][r] + bq4[r]);
                    *(bf16x4*)&BufA[(32 * h0 + 16 * mm + lr) * XSTR + ccl] = v4;
                }
            }
        }

        // Q on the fly: rows 16*m2, channels hg*96..+96 (tiles qt = hg*6+u), from cached X-frags
        unsigned pkq[6][2];
        for (int u = 0; u < 6; ++u) {
            const int qt = hg * 6 + u;
            const bf16* wp = wqkvT + (size_t)(qt * 16 + lr) * CDIM + lq * 8;
            bf16x8 bfrag[6];
            #pragma unroll
            for (int k = 0; k < 6; ++k) bfrag[k] = *(const bf16x8*)(wp + k * 32);
            f32x4 acc = f32x4{0.f, 0.f, 0.f, 0.f};
            #pragma unroll
            for (int k = 0; k < 6; ++k)
                acc = __builtin_amdgcn_mfma_f32_16x16x32_bf16(bfrag[k], afrag[mm_sel][k], acc, 0, 0, 0);
            const f32x4 bq4 = *(const f32x4*)&b_qkv[qt * 16 + 4 * lq];
            pkq[u][0] = pack2bf(acc[0] + bq4[0], acc[1] + bq4[1]);
            pkq[u][1] = pack2bf(acc[2] + bq4[2], acc[3] + bq4[3]);
        }
        // D-layout -> B-frag conversion (verified P^T machinery):
        // group1: u0..3 -> qf[0] (ch 0..31), qf[1] (ch 32..63); group2: u4,5 -> qf[2] (ch 64..95)
        const int src0 = lr + 32 * (lq & 1);
        u32x4 w0, w1, w2;
        #pragma unroll
        for (int w = 0; w < 4; ++w) {
            int srcl = src0 + 16 * (w >> 1);
            int s = w & 1;
            unsigned a0 = (unsigned)__shfl((int)pkq[0][s], srcl);
            unsigned b0 = (unsigned)__shfl((int)pkq[1][s], srcl);
            unsigned a1 = (unsigned)__shfl((int)pkq[2][s], srcl);
            unsigned b1 = (unsigned)__shfl((int)pkq[3][s], srcl);
            unsigned a2 = (unsigned)__shfl((int)pkq[4][s], srcl);
            unsigned b2 = (unsigned)__shfl((int)pkq[5][s], srcl);
            w0[w] = (lq & 2) ? b0 : a0;
            w1[w] = (lq & 2) ? b1 : a1;
            w2[w] = (lq & 2) ? b2 : a2;
        }
        qf[0] = __builtin_bit_cast(bf16x8, w0);
        qf[1] = __builtin_bit_cast(bf16x8, w1);
        qf[2] = __builtin_bit_cast(bf16x8, w2);
    }
    __syncthreads();   // K fully written

    // ---- phase 2a: QK^T (all 3 heads) reading K from BufA ----
    const int cls = ((wy == 7) ? 2 : 0) | ((wx == 7) ? 1 : 0);
    const bf16* bgp = biasG + (((size_t)cls * 6 + hg * 3) * 64 + (16 * m2 + lr)) * 64 + 4 * lq;
    f32x4 st[3][4];
    #pragma unroll
    for (int hh = 0; hh < 3; ++hh) {
        const int h = hg * 3 + hh;
        #pragma unroll
        for (int n = 0; n < 4; ++n) {
            bf16x8 ak = *(const bf16x8*)&BufA[(16 * n + lr) * XSTR + h * 32 + lq * 8];
            st[hh][n] = __builtin_amdgcn_mfma_f32_16x16x32_bf16(ak, qf[hh], f32x4{0.f, 0.f, 0.f, 0.f}, 0, 0, 0);
        }
    }
    // prefetch head-0 bias row into the barrier shadow
    bf16x4 b40[4];
    #pragma unroll
    for (int n = 0; n < 4; ++n) b40[n] = *(const bf16x4*)(bgp + 16 * n);
    __syncthreads();   // all QK^T reads of K done -> BufA reusable for O

    // ---- phase 2b: softmax + in-register P^T + PV; O overwrites K in BufA ----
    {
        const int src0 = lr + 32 * (lq & 1);
        const float SC = SCALE * LOG2E;
        #pragma unroll
        for (int hh = 0; hh < 3; ++hh) {
            const int h = hg * 3 + hh;
            bf16x4 b4[4];
            if (hh == 0) {
                #pragma unroll
                for (int n = 0; n < 4; ++n) b4[n] = b40[n];
            } else {
                #pragma unroll
                for (int n = 0; n < 4; ++n) b4[n] = *(const bf16x4*)(bgp + hh * 4096 + 16 * n);
            }
            float p[4][4];
            float umax = -1e30f;
            #pragma unroll
            for (int n = 0; n < 4; ++n)
                #pragma unroll
                for (int r = 0; r < 4; ++r) {
                    float v = fmaf(st[hh][n][r], SC, (float)b4[n][r]);
                    p[n][r] = v;
                    umax = fmaxf(umax, v);
                }
            umax = fmaxf(umax, __shfl_xor(umax, 16));
            umax = fmaxf(umax, __shfl_xor(umax, 32));
            float sum = 0.f;
            #pragma unroll
            for (int n = 0; n < 4; ++n)
                #pragma unroll
                for (int r = 0; r < 4; ++r) {
                    float e = exp2f(p[n][r] - umax);
                    p[n][r] = e; sum += e;
                }
            sum += __shfl_xor(sum, 16);
            sum += __shfl_xor(sum, 32);
            const float inv = 1.f / sum;
            unsigned pk[4][2];
            #pragma unroll
            for (int n = 0; n < 4; ++n)
                #pragma unroll
                for (int s = 0; s < 2; ++s)
                    pk[n][s] = pack2bf(p[n][2 * s] * inv, p[n][2 * s + 1] * inv);
            // shuffle D-layout -> B-frag(P^T)
            u32x4 ptw0, ptw1;
            #pragma unroll
            for (int w = 0; w < 4; ++w) {
                int srcl = src0 + 16 * (w >> 1);
                int s = w & 1;
                unsigned a0 = (unsigned)__shfl((int)pk[0][s], srcl);
                unsigned b0 = (unsigned)__shfl((int)pk[1][s], srcl);
                unsigned a1 = (unsigned)__shfl((int)pk[2][s], srcl);
                unsigned b1 = (unsigned)__shfl((int)pk[3][s], srcl);
                ptw0[w] = (lq & 2) ? b0 : a0;
                ptw1[w] = (lq & 2) ? b1 : a1;
            }
            bf16x8 bp0 = __builtin_bit_cast(bf16x8, ptw0);
            bf16x8 bp1 = __builtin_bit_cast(bf16x8, ptw1);
            // PV: O^T = V^T · P^T
            f32x4 ot[2];
            #pragma unroll
            for (int dt = 0; dt < 2; ++dt) {
                const bf16* vrow = &VTs[(h * 32 + 16 * dt + lr) * VSTR + lq * 8];
                bf16x8 av0 = *(const bf16x8*)(vrow);
                bf16x8 av1 = *(const bf16x8*)(vrow + 32);
                ot[dt] = __builtin_amdgcn_mfma_f32_16x16x32_bf16(av0, bp0, f32x4{0.f, 0.f, 0.f, 0.f}, 0, 0, 0);
                ot[dt] = __builtin_amdgcn_mfma_f32_16x16x32_bf16(av1, bp1, ot[dt], 0, 0, 0);
            }
            // O^T[d][i] -> BufA[i][d] (over K; wave-private (m2,h) region)
            #pragma unroll
            for (int dt = 0; dt < 2; ++dt) {
                bf16x4 o4;
                #pragma unroll
                for (int r = 0; r < 4; ++r) o4[r] = (bf16)ot[dt][r];
                *(bf16x4*)&BufA[(16 * m2 + lr) * XSTR + h * 32 + 16 * dt + 4 * lq] = o4;
            }
        }
    }
    __syncthreads();

    // ---- phase 3: proj + bias, swapped, dual-acc; wave = (half = w&1, cg3 = w>>1), 3 units ----
    {
        const int half = wave & 1;
        const int cg3  = wave >> 1;
        bf16x8 ofrag[2][6];
        #pragma unroll
        for (int mm = 0; mm < 2; ++mm)
            #pragma unroll
            for (int k = 0; k < 6; ++k)
                ofrag[mm][k] = *(const bf16x8*)&BufA[(32 * half + 16 * mm + lr) * XSTR + k * 32 + lq * 8];
        float* orow[2];
        bool   valid[2];
        #pragma unroll
        for (int mm = 0; mm < 2; ++mm) {
            const int row = 32 * half + 16 * mm + lr;
            valid[mm] = row < NTOK;
            int rr = valid[mm] ? row : 0;
            int ty = rr / 7, tx = rr % 7;
            int oy = wy * 7 + ty + SHIFTV; if (oy >= IMG) oy -= IMG;
            int ox = wx * 7 + tx + SHIFTV; if (ox >= IMG) ox -= IMG;
            orow[mm] = out + (((size_t)bimg * IMG + oy) * IMG + ox) * CDIM;
        }

        for (int s3 = 0; s3 < 3; ++s3) {
            const int nt = cg3 + 4 * s3;
            const bf16* wp = wprojT + (size_t)(nt * 16 + lr) * CDIM + lq * 8;
            bf16x8 wfrag[6];
            #pragma unroll
            for (int k = 0; k < 6; ++k) wfrag[k] = *(const bf16x8*)(wp + k * 32);
            f32x4 acc[2];
            acc[0] = f32x4{0.f, 0.f, 0.f, 0.f}; acc[1] = f32x4{0.f, 0.f, 0.f, 0.f};
            #pragma unroll
            for (int k = 0; k < 6; ++k)
                #pragma unroll
                for (int mm = 0; mm < 2; ++mm)
                    acc[mm] = __builtin_amdgcn_mfma_f32_16x16x32_bf16(wfrag[k], ofrag[mm][k], acc[mm], 0, 0, 0);
            const int c0 = nt * 16 + 4 * lq;
            const f32x4 bp = *(const f32x4*)&b_proj[c0];
            #pragma unroll
            for (int mm = 0; mm < 2; ++mm) {
                if (valid[mm]) {
                    f32x4 v;
                    #pragma unroll
                    for (int r = 0; r < 4; ++r) v[r] = acc[mm][r] + bp[r];
                    *(f32x4*)&orow[mm][c0] = v;
                }
            }
        }
    }
}

extern "C" void kernel_launch(void* const* d_in, const int* in_sizes, int n_in,
                              void* d_out, int out_size, void* d_ws, size_t ws_size,
                              hipStream_t stream) {
    const float* x           = (const float*)d_in[0];
    const float* gamma       = (const float*)d_in[1];
    const float* beta        = (const float*)d_in[2];
    const float* w_qkv       = (const float*)d_in[3];
    const float* b_qkv       = (const float*)d_in[4];
    const float* rel_table   = (const float*)d_in[5];
    const float* w_proj      = (const float*)d_in[6];
    const float* b_proj      = (const float*)d_in[7];
    // d_in[8] = mask_matrix: folded into biasG table
    float* out = (float*)d_out;

    bf16* wqkvT  = (bf16*)d_ws;                                    // 221184 B
    bf16* wprojT = (bf16*)((char*)d_ws + 221184);                  //  73728 B
    bf16* biasG  = (bf16*)((char*)d_ws + 221184 + 73728);          // 196608 B

    prep_weights<<<432, 256, 0, stream>>>(w_qkv, w_proj, rel_table, wqkvT, wprojT, biasG);
    swin_block<<<4096, 512, 0, stream>>>(x, gamma, beta, wqkvT, b_qkv, biasG,
                                         wprojT, b_proj, out);
}

// Round 7
// 679.963 us; speedup vs baseline: 1.0457x; 1.0457x over previous
//
#include <hip/hip_runtime.h>
#include <hip/hip_bf16.h>
#include <math.h>

typedef __bf16 bf16;
typedef __bf16 bf16x4 __attribute__((ext_vector_type(4)));
typedef __bf16 bf16x8 __attribute__((ext_vector_type(8)));
typedef float f32x4 __attribute__((ext_vector_type(4)));
typedef unsigned int u32x4 __attribute__((ext_vector_type(4)));

#define NHEADS 6
#define CDIM 192
#define IMG 56
#define NTOK 49
#define SHIFTV 3
#define XSTR 200   // padded row stride (bf16) for BufA: 400 B
#define VSTR 72    // padded stride for VT: 144 B
#define LOG2E 1.4426950408889634f
#define SCALE 0.17677669529663687f

static __device__ __forceinline__ unsigned pack2bf(float lo, float hi) {
    unsigned short a = __builtin_bit_cast(unsigned short, (bf16)lo);
    unsigned short b = __builtin_bit_cast(unsigned short, (bf16)hi);
    return (unsigned)a | ((unsigned)b << 16);
}

// ---- prep: weight transpose->bf16 + fused (bias+mask)*log2e table ----
// biasG[class c][head h][i 64][j 64], c = (wy==7)*2 + (wx==7)
__global__ void prep_weights(const float* __restrict__ w_qkv, const float* __restrict__ w_proj,
                             const float* __restrict__ rel_table,
                             bf16* __restrict__ wqkvT, bf16* __restrict__ wprojT,
                             bf16* __restrict__ biasG) {
    int i = blockIdx.x * 256 + threadIdx.x;
    if (i < 576 * 192) {
        int n = i / 192, k = i % 192;
        wqkvT[i] = (bf16)w_qkv[k * 576 + n];
    }
    if (i < 192 * 192) {
        int n = i / 192, k = i % 192;
        wprojT[i] = (bf16)w_proj[k * 192 + n];
    }
    if (i < 24 * 64 * 64) {
        int j = i & 63, ii = (i >> 6) & 63, t = i >> 12;
        int h = t % 6, c = t / 6;
        float val = -100.f;
        if (ii < 49 && j < 49) {
            int iy = ii / 7, ix = ii % 7, jy = j / 7, jx = j % 7;
            int rp = (iy - jy + 6) * 13 + (ix - jx + 6);
            bool ym = !(c & 2) || ((iy < 4) == (jy < 4));
            bool xm = !(c & 1) || ((ix < 4) == (jx < 4));
            val = rel_table[rp * 6 + h] + ((ym && xm) ? 0.f : -100.f);
        }
        biasG[i] = (bf16)(val * LOG2E);
    }
}

__global__ __launch_bounds__(512, 6) void swin_block(
    const float* __restrict__ x, const float* __restrict__ gamma, const float* __restrict__ beta,
    const bf16* __restrict__ wqkvT, const float* __restrict__ b_qkv,
    const bf16* __restrict__ biasG, const bf16* __restrict__ wprojT,
    const float* __restrict__ b_proj, float* __restrict__ out)
{
    __shared__ __align__(16) bf16 BufA[64 * XSTR];     // X (ph0-1) -> K (ph1-2) -> O (ph2-3)
    __shared__ __align__(16) bf16 VTs[CDIM * VSTR];    // V transposed: [channel][token]
    // total 53248 B -> 3 blocks/CU

    const int blk  = blockIdx.x;
    const int bimg = blk >> 6;
    const int wy   = (blk >> 3) & 7;
    const int wx   = blk & 7;
    const int tid  = threadIdx.x;
    const int wave = tid >> 6;   // 0..7
    const int lane = tid & 63;
    const int lr   = lane & 15;
    const int lq   = lane >> 4;

    // wave roles: phase1 K/V: half h0, col-group cg; phase2: row-tile m2, head-group hg
    const int h0     = wave & 1;
    const int cg     = (wave >> 1) & 3;
    const int mm_sel = (wave >> 1) & 1;
    const int m2     = 2 * h0 + mm_sel;
    const int hg     = wave >> 2;

    // ---- phase 0: shifted-window load + LayerNorm -> BufA (bf16), rows 49..63 zero ----
    {
        const float g0 = gamma[lane], g1 = gamma[lane + 64], g2 = gamma[lane + 128];
        const float b0 = beta[lane],  b1 = beta[lane + 64],  b2 = beta[lane + 128];
        for (int t = wave; t < 64; t += 8) {
            if (t < NTOK) {
                int ty = t / 7, tx = t % 7;
                int oy = wy * 7 + ty + SHIFTV; if (oy >= IMG) oy -= IMG;
                int ox = wx * 7 + tx + SHIFTV; if (ox >= IMG) ox -= IMG;
                const float* xp = x + (((size_t)bimg * IMG + oy) * IMG + ox) * CDIM;
                float v0 = xp[lane], v1 = xp[lane + 64], v2 = xp[lane + 128];
                float s = v0 + v1 + v2, ss = v0 * v0 + v1 * v1 + v2 * v2;
                #pragma unroll
                for (int off = 32; off; off >>= 1) { s += __shfl_xor(s, off); ss += __shfl_xor(ss, off); }
                float mu  = s * (1.f / 192.f);
                float var = ss * (1.f / 192.f) - mu * mu;
                float rs  = rsqrtf(var + 1e-5f);
                BufA[t * XSTR + lane      ] = (bf16)((v0 - mu) * rs * g0 + b0);
                BufA[t * XSTR + lane + 64 ] = (bf16)((v1 - mu) * rs * g1 + b1);
                BufA[t * XSTR + lane + 128] = (bf16)((v2 - mu) * rs * g2 + b2);
            } else {
                BufA[t * XSTR + lane      ] = (bf16)0.f;
                BufA[t * XSTR + lane + 64 ] = (bf16)0.f;
                BufA[t * XSTR + lane + 128] = (bf16)0.f;
            }
        }
    }
    __syncthreads();

    // ---- phase 1: cache X; K -> BufA (over X), V^T -> VTs; Q on-the-fly -> registers ----
    bf16x8 qf[3];
    {
        bf16x8 afrag[2][6];
        #pragma unroll
        for (int mm = 0; mm < 2; ++mm)
            #pragma unroll
            for (int k = 0; k < 6; ++k)
                afrag[mm][k] = *(const bf16x8*)&BufA[(32 * h0 + 16 * mm + lr) * XSTR + k * 32 + lq * 8];
        __syncthreads();   // all waves cached X before K overwrites BufA

        for (int t = 0; t < 6; ++t) {
            const int ntkv = cg + 4 * t;
            const bf16* wp = wqkvT + (size_t)((12 + ntkv) * 16 + lr) * CDIM + lq * 8;
            bf16x8 bfrag[6];
            #pragma unroll
            for (int k = 0; k < 6; ++k) bfrag[k] = *(const bf16x8*)(wp + k * 32);
            f32x4 acc[2];
            acc[0] = f32x4{0.f, 0.f, 0.f, 0.f}; acc[1] = f32x4{0.f, 0.f, 0.f, 0.f};
            if (ntkv >= 12) {
                // V: unswapped -> D: channel = (ntkv-12)*16+lr, token packed 4lq+r
                #pragma unroll
                for (int k = 0; k < 6; ++k)
                    #pragma unroll
                    for (int mm = 0; mm < 2; ++mm)
                        acc[mm] = __builtin_amdgcn_mfma_f32_16x16x32_bf16(afrag[mm][k], bfrag[k], acc[mm], 0, 0, 0);
                const int cc   = (ntkv - 12) * 16 + lr;
                const float bb = b_qkv[384 + cc];
                #pragma unroll
                for (int mm = 0; mm < 2; ++mm) {
                    bf16x4 v4;
                    #pragma unroll
                    for (int r = 0; r < 4; ++r) v4[r] = (bf16)(acc[mm][r] + bb);
                    *(bf16x4*)&VTs[cc * VSTR + 32 * h0 + 16 * mm + 4 * lq] = v4;
                }
            } else {
                // K: swapped -> D: token = 32h0+16mm+lr, channel packed ntkv*16+4lq+r
                #pragma unroll
                for (int k = 0; k < 6; ++k)
                    #pragma unroll
                    for (int mm = 0; mm < 2; ++mm)
                        acc[mm] = __builtin_amdgcn_mfma_f32_16x16x32_bf16(bfrag[k], afrag[mm][k], acc[mm], 0, 0, 0);
                const int ccl = ntkv * 16 + 4 * lq;
                const f32x4 bq4 = *(const f32x4*)&b_qkv[192 + ccl];
                #pragma unroll
                for (int mm = 0; mm < 2; ++mm) {
                    bf16x4 v4;
                    #pragma unroll
                    for (int r = 0; r < 4; ++r) v4[r] = (bf16)(acc[mm][r] + bq4[r]);
                    *(bf16x4*)&BufA[(32 * h0 + 16 * mm + lr) * XSTR + ccl] = v4;
                }
            }
        }

        // Q on the fly: rows 16*m2, channels hg*96..+95 (tiles qt = hg*6+u)
        unsigned pkq[6][2];
        for (int u = 0; u < 6; ++u) {
            const int qt = hg * 6 + u;
            const bf16* wp = wqkvT + (size_t)(qt * 16 + lr) * CDIM + lq * 8;
            bf16x8 bfrag[6];
            #pragma unroll
            for (int k = 0; k < 6; ++k) bfrag[k] = *(const bf16x8*)(wp + k * 32);
            f32x4 acc = f32x4{0.f, 0.f, 0.f, 0.f};
            #pragma unroll
            for (int k = 0; k < 6; ++k)
                acc = __builtin_amdgcn_mfma_f32_16x16x32_bf16(bfrag[k], afrag[mm_sel][k], acc, 0, 0, 0);
            const f32x4 bq4 = *(const f32x4*)&b_qkv[qt * 16 + 4 * lq];
            pkq[u][0] = pack2bf(acc[0] + bq4[0], acc[1] + bq4[1]);
            pkq[u][1] = pack2bf(acc[2] + bq4[2], acc[3] + bq4[3]);
        }
        // D-layout -> B-frag conversion (verified machinery)
        const int src0 = lr + 32 * (lq & 1);
        u32x4 w0, w1, w2;
        #pragma unroll
        for (int w = 0; w < 4; ++w) {
            int srcl = src0 + 16 * (w >> 1);
            int s = w & 1;
            unsigned a0 = (unsigned)__shfl((int)pkq[0][s], srcl);
            unsigned b0 = (unsigned)__shfl((int)pkq[1][s], srcl);
            unsigned a1 = (unsigned)__shfl((int)pkq[2][s], srcl);
            unsigned b1 = (unsigned)__shfl((int)pkq[3][s], srcl);
            unsigned a2 = (unsigned)__shfl((int)pkq[4][s], srcl);
            unsigned b2 = (unsigned)__shfl((int)pkq[5][s], srcl);
            w0[w] = (lq & 2) ? b0 : a0;
            w1[w] = (lq & 2) ? b1 : a1;
            w2[w] = (lq & 2) ? b2 : a2;
        }
        qf[0] = __builtin_bit_cast(bf16x8, w0);
        qf[1] = __builtin_bit_cast(bf16x8, w1);
        qf[2] = __builtin_bit_cast(bf16x8, w2);
    }
    __syncthreads();   // K fully written

    // ---- phase 2: head-at-a-time attention; one barrier/head between QK^T(h) and O-write(h) ----
    {
        const int cls = ((wy == 7) ? 2 : 0) | ((wx == 7) ? 1 : 0);
        const bf16* bgp = biasG + (((size_t)cls * 6 + hg * 3) * 64 + (16 * m2 + lr)) * 64 + 4 * lq;
        const int src0 = lr + 32 * (lq & 1);
        const float SC = SCALE * LOG2E;

        #pragma unroll
        for (int hh = 0; hh < 3; ++hh) {
            const int h = hg * 3 + hh;
            // QK^T(h): reads K cols h*32..+31 (untouched by prior O-writes)
            f32x4 st[4];
            #pragma unroll
            for (int n = 0; n < 4; ++n) {
                bf16x8 ak = *(const bf16x8*)&BufA[(16 * n + lr) * XSTR + h * 32 + lq * 8];
                st[n] = __builtin_amdgcn_mfma_f32_16x16x32_bf16(ak, qf[hh], f32x4{0.f, 0.f, 0.f, 0.f}, 0, 0, 0);
            }
            bf16x4 b4[4];
            #pragma unroll
            for (int n = 0; n < 4; ++n) b4[n] = *(const bf16x4*)(bgp + hh * 4096 + 16 * n);
            __syncthreads();   // all QK^T(h) reads done -> K[h] columns reusable for O

            float p[4][4];
            float umax = -1e30f;
            #pragma unroll
            for (int n = 0; n < 4; ++n)
                #pragma unroll
                for (int r = 0; r < 4; ++r) {
                    float v = fmaf(st[n][r], SC, (float)b4[n][r]);
                    p[n][r] = v;
                    umax = fmaxf(umax, v);
                }
            umax = fmaxf(umax, __shfl_xor(umax, 16));
            umax = fmaxf(umax, __shfl_xor(umax, 32));
            float sum = 0.f;
            #pragma unroll
            for (int n = 0; n < 4; ++n)
                #pragma unroll
                for (int r = 0; r < 4; ++r) {
                    float e = exp2f(p[n][r] - umax);
                    p[n][r] = e; sum += e;
                }
            sum += __shfl_xor(sum, 16);
            sum += __shfl_xor(sum, 32);
            const float inv = 1.f / sum;
            unsigned pk[4][2];
            #pragma unroll
            for (int n = 0; n < 4; ++n)
                #pragma unroll
                for (int s = 0; s < 2; ++s)
                    pk[n][s] = pack2bf(p[n][2 * s] * inv, p[n][2 * s + 1] * inv);
            u32x4 ptw0, ptw1;
            #pragma unroll
            for (int w = 0; w < 4; ++w) {
                int srcl = src0 + 16 * (w >> 1);
                int s = w & 1;
                unsigned a0 = (unsigned)__shfl((int)pk[0][s], srcl);
                unsigned b0 = (unsigned)__shfl((int)pk[1][s], srcl);
                unsigned a1 = (unsigned)__shfl((int)pk[2][s], srcl);
                unsigned b1 = (unsigned)__shfl((int)pk[3][s], srcl);
                ptw0[w] = (lq & 2) ? b0 : a0;
                ptw1[w] = (lq & 2) ? b1 : a1;
            }
            bf16x8 bp0 = __builtin_bit_cast(bf16x8, ptw0);
            bf16x8 bp1 = __builtin_bit_cast(bf16x8, ptw1);
            // PV: O^T = V^T · P^T
            f32x4 ot[2];
            #pragma unroll
            for (int dt = 0; dt < 2; ++dt) {
                const bf16* vrow = &VTs[(h * 32 + 16 * dt + lr) * VSTR + lq * 8];
                bf16x8 av0 = *(const bf16x8*)(vrow);
                bf16x8 av1 = *(const bf16x8*)(vrow + 32);
                ot[dt] = __builtin_amdgcn_mfma_f32_16x16x32_bf16(av0, bp0, f32x4{0.f, 0.f, 0.f, 0.f}, 0, 0, 0);
                ot[dt] = __builtin_amdgcn_mfma_f32_16x16x32_bf16(av1, bp1, ot[dt], 0, 0, 0);
            }
            // O^T[d][i] -> BufA[i][h*32+d] (over K[h]; wave-private (m2,h) region)
            #pragma unroll
            for (int dt = 0; dt < 2; ++dt) {
                bf16x4 o4;
                #pragma unroll
                for (int r = 0; r < 4; ++r) o4[r] = (bf16)ot[dt][r];
                *(bf16x4*)&BufA[(16 * m2 + lr) * XSTR + h * 32 + 16 * dt + 4 * lq] = o4;
            }
        }
    }
    __syncthreads();

    // ---- phase 3: proj + bias, swapped, dual-acc; wave = (half = w&1, cg3 = w>>1), 3 units ----
    {
        const int half = wave & 1;
        const int cg3  = wave >> 1;
        bf16x8 ofrag[2][6];
        #pragma unroll
        for (int mm = 0; mm < 2; ++mm)
            #pragma unroll
            for (int k = 0; k < 6; ++k)
                ofrag[mm][k] = *(const bf16x8*)&BufA[(32 * half + 16 * mm + lr) * XSTR + k * 32 + lq * 8];
        float* orow[2];
        bool   valid[2];
        #pragma unroll
        for (int mm = 0; mm < 2; ++mm) {
            const int row = 32 * half + 16 * mm + lr;
            valid[mm] = row < NTOK;
            int rr = valid[mm] ? row : 0;
            int ty = rr / 7, tx = rr % 7;
            int oy = wy * 7 + ty + SHIFTV; if (oy >= IMG) oy -= IMG;
            int ox = wx * 7 + tx + SHIFTV; if (ox >= IMG) ox -= IMG;
            orow[mm] = out + (((size_t)bimg * IMG + oy) * IMG + ox) * CDIM;
        }

        for (int s3 = 0; s3 < 3; ++s3) {
            const int nt = cg3 + 4 * s3;
            const bf16* wp = wprojT + (size_t)(nt * 16 + lr) * CDIM + lq * 8;
            bf16x8 wfrag[6];
            #pragma unroll
            for (int k = 0; k < 6; ++k) wfrag[k] = *(const bf16x8*)(wp + k * 32);
            f32x4 acc[2];
            acc[0] = f32x4{0.f, 0.f, 0.f, 0.f}; acc[1] = f32x4{0.f, 0.f, 0.f, 0.f};
            #pragma unroll
            for (int k = 0; k < 6; ++k)
                #pragma unroll
                for (int mm = 0; mm < 2; ++mm)
                    acc[mm] = __builtin_amdgcn_mfma_f32_16x16x32_bf16(wfrag[k], ofrag[mm][k], acc[mm], 0, 0, 0);
            const int c0 = nt * 16 + 4 * lq;
            const f32x4 bp = *(const f32x4*)&b_proj[c0];
            #pragma unroll
            for (int mm = 0; mm < 2; ++mm) {
                if (valid[mm]) {
                    f32x4 v;
                    #pragma unroll
                    for (int r = 0; r < 4; ++r) v[r] = acc[mm][r] + bp[r];
                    *(f32x4*)&orow[mm][c0] = v;
                }
            }
        }
    }
}

extern "C" void kernel_launch(void* const* d_in, const int* in_sizes, int n_in,
                              void* d_out, int out_size, void* d_ws, size_t ws_size,
                              hipStream_t stream) {
    const float* x           = (const float*)d_in[0];
    const float* gamma       = (const float*)d_in[1];
    const float* beta        = (const float*)d_in[2];
    const float* w_qkv       = (const float*)d_in[3];
    const float* b_qkv       = (const float*)d_in[4];
    const float* rel_table   = (const float*)d_in[5];
    const float* w_proj      = (const float*)d_in[6];
    const float* b_proj      = (const float*)d_in[7];
    // d_in[8] = mask_matrix: folded into biasG table
    float* out = (float*)d_out;

    bf16* wqkvT  = (bf16*)d_ws;                                    // 221184 B
    bf16* wprojT = (bf16*)((char*)d_ws + 221184);                  //  73728 B
    bf16* biasG  = (bf16*)((char*)d_ws + 221184 + 73728);          // 196608 B

    prep_weights<<<432, 256, 0, stream>>>(w_qkv, w_proj, rel_table, wqkvT, wprojT, biasG);
    swin_block<<<4096, 512, 0, stream>>>(x, gamma, beta, wqkvT, b_qkv, biasG,
                                         wprojT, b_proj, out);
}

// Round 8
// 611.068 us; speedup vs baseline: 1.1636x; 1.1127x over previous
//
#include <hip/hip_runtime.h>
#include <hip/hip_bf16.h>
#include <math.h>

typedef __bf16 bf16;
typedef __bf16 bf16x4 __attribute__((ext_vector_type(4)));
typedef __bf16 bf16x8 __attribute__((ext_vector_type(8)));
typedef float f32x4 __attribute__((ext_vector_type(4)));
typedef unsigned int u32x4 __attribute__((ext_vector_type(4)));

#define NHEADS 6
#define CDIM 192
#define IMG 56
#define NTOK 49
#define SHIFTV 3
#define XSTR 200   // padded row stride (bf16) for BufA: 400 B
#define VSTR 72    // padded stride for VT: 144 B
#define LOG2E 1.4426950408889634f
#define SCALE 0.17677669529663687f

static __device__ __forceinline__ unsigned pack2bf(float lo, float hi) {
    unsigned short a = __builtin_bit_cast(unsigned short, (bf16)lo);
    unsigned short b = __builtin_bit_cast(unsigned short, (bf16)hi);
    return (unsigned)a | ((unsigned)b << 16);
}

// ---- prep: weight transpose->bf16 + fused (bias+mask)*log2e table ----
// biasG[class c][head h][i 64][j 64], c = (wy==7)*2 + (wx==7)
__global__ void prep_weights(const float* __restrict__ w_qkv, const float* __restrict__ w_proj,
                             const float* __restrict__ rel_table,
                             bf16* __restrict__ wqkvT, bf16* __restrict__ wprojT,
                             bf16* __restrict__ biasG) {
    int i = blockIdx.x * 256 + threadIdx.x;
    if (i < 576 * 192) {
        int n = i / 192, k = i % 192;
        wqkvT[i] = (bf16)w_qkv[k * 576 + n];
    }
    if (i < 192 * 192) {
        int n = i / 192, k = i % 192;
        wprojT[i] = (bf16)w_proj[k * 192 + n];
    }
    if (i < 24 * 64 * 64) {
        int j = i & 63, ii = (i >> 6) & 63, t = i >> 12;
        int h = t % 6, c = t / 6;
        float val = -100.f;
        if (ii < 49 && j < 49) {
            int iy = ii / 7, ix = ii % 7, jy = j / 7, jx = j % 7;
            int rp = (iy - jy + 6) * 13 + (ix - jx + 6);
            bool ym = !(c & 2) || ((iy < 4) == (jy < 4));
            bool xm = !(c & 1) || ((ix < 4) == (jx < 4));
            val = rel_table[rp * 6 + h] + ((ym && xm) ? 0.f : -100.f);
        }
        biasG[i] = (bf16)(val * LOG2E);
    }
}

__global__ __launch_bounds__(512, 6) void swin_block(
    const float* __restrict__ x, const float* __restrict__ gamma, const float* __restrict__ beta,
    const bf16* __restrict__ wqkvT, const float* __restrict__ b_qkv,
    const bf16* __restrict__ biasG, const bf16* __restrict__ wprojT,
    const float* __restrict__ b_proj, float* __restrict__ out)
{
    __shared__ __align__(16) bf16 BufA[64 * XSTR];     // X (ph0-1) -> K (ph1-2) -> O (ph2-3)
    __shared__ __align__(16) bf16 VTs[CDIM * VSTR];    // V transposed: [channel][token]
    // total 53248 B -> 3 blocks/CU

    const int blk  = blockIdx.x;
    const int bimg = blk >> 6;
    const int wy   = (blk >> 3) & 7;
    const int wx   = blk & 7;
    const int tid  = threadIdx.x;
    const int wave = tid >> 6;   // 0..7
    const int lane = tid & 63;
    const int lr   = lane & 15;
    const int lq   = lane >> 4;

    // wave roles
    const int h0     = wave & 1;
    const int cg     = (wave >> 1) & 3;
    const int mm_sel = (wave >> 1) & 1;
    const int m2     = 2 * h0 + mm_sel;
    const int hg     = wave >> 2;

    // ---- phase 0: shifted-window load + LayerNorm -> BufA (bf16), rows 49..63 zero ----
    {
        const float g0 = gamma[lane], g1 = gamma[lane + 64], g2 = gamma[lane + 128];
        const float b0 = beta[lane],  b1 = beta[lane + 64],  b2 = beta[lane + 128];
        for (int t = wave; t < 64; t += 8) {
            if (t < NTOK) {
                int ty = t / 7, tx = t % 7;
                int oy = wy * 7 + ty + SHIFTV; if (oy >= IMG) oy -= IMG;
                int ox = wx * 7 + tx + SHIFTV; if (ox >= IMG) ox -= IMG;
                const float* xp = x + (((size_t)bimg * IMG + oy) * IMG + ox) * CDIM;
                float v0 = xp[lane], v1 = xp[lane + 64], v2 = xp[lane + 128];
                float s = v0 + v1 + v2, ss = v0 * v0 + v1 * v1 + v2 * v2;
                #pragma unroll
                for (int off = 32; off; off >>= 1) { s += __shfl_xor(s, off); ss += __shfl_xor(ss, off); }
                float mu  = s * (1.f / 192.f);
                float var = ss * (1.f / 192.f) - mu * mu;
                float rs  = rsqrtf(var + 1e-5f);
                BufA[t * XSTR + lane      ] = (bf16)((v0 - mu) * rs * g0 + b0);
                BufA[t * XSTR + lane + 64 ] = (bf16)((v1 - mu) * rs * g1 + b1);
                BufA[t * XSTR + lane + 128] = (bf16)((v2 - mu) * rs * g2 + b2);
            } else {
                BufA[t * XSTR + lane      ] = (bf16)0.f;
                BufA[t * XSTR + lane + 64 ] = (bf16)0.f;
                BufA[t * XSTR + lane + 128] = (bf16)0.f;
            }
        }
    }
    __syncthreads();

    // ---- phase 1: cache X; K -> BufA (over X), V^T -> VTs; Q on-the-fly -> registers ----
    bf16x8 qf[3];
    {
        bf16x8 afrag[2][6];
        #pragma unroll
        for (int mm = 0; mm < 2; ++mm)
            #pragma unroll
            for (int k = 0; k < 6; ++k)
                afrag[mm][k] = *(const bf16x8*)&BufA[(32 * h0 + 16 * mm + lr) * XSTR + k * 32 + lq * 8];
        __syncthreads();   // all waves cached X before K overwrites BufA

        // K tiles: ntk = cg + 4t, t=0..2 (all < 12)
        #pragma unroll
        for (int t = 0; t < 3; ++t) {
            const int ntk = cg + 4 * t;
            const bf16* wp = wqkvT + (size_t)((12 + ntk) * 16 + lr) * CDIM + lq * 8;
            bf16x8 bfrag[6];
            #pragma unroll
            for (int k = 0; k < 6; ++k) bfrag[k] = *(const bf16x8*)(wp + k * 32);
            f32x4 acc[2];
            acc[0] = f32x4{0.f, 0.f, 0.f, 0.f}; acc[1] = f32x4{0.f, 0.f, 0.f, 0.f};
            // swapped -> D: token = 32h0+16mm+lr, channel packed ntk*16+4lq+r
            #pragma unroll
            for (int k = 0; k < 6; ++k)
                #pragma unroll
                for (int mm = 0; mm < 2; ++mm)
                    acc[mm] = __builtin_amdgcn_mfma_f32_16x16x32_bf16(bfrag[k], afrag[mm][k], acc[mm], 0, 0, 0);
            const int ccl = ntk * 16 + 4 * lq;
            const f32x4 bq4 = *(const f32x4*)&b_qkv[192 + ccl];
            #pragma unroll
            for (int mm = 0; mm < 2; ++mm) {
                bf16x4 v4;
                #pragma unroll
                for (int r = 0; r < 4; ++r) v4[r] = (bf16)(acc[mm][r] + bq4[r]);
                *(bf16x4*)&BufA[(32 * h0 + 16 * mm + lr) * XSTR + ccl] = v4;
            }
        }
        // V tiles: ntv = cg + 4t, t=0..2 (channel tile index into VTs)
        #pragma unroll
        for (int t = 0; t < 3; ++t) {
            const int ntv = cg + 4 * t;
            const bf16* wp = wqkvT + (size_t)((24 + ntv) * 16 + lr) * CDIM + lq * 8;
            bf16x8 bfrag[6];
            #pragma unroll
            for (int k = 0; k < 6; ++k) bfrag[k] = *(const bf16x8*)(wp + k * 32);
            f32x4 acc[2];
            acc[0] = f32x4{0.f, 0.f, 0.f, 0.f}; acc[1] = f32x4{0.f, 0.f, 0.f, 0.f};
            // unswapped -> D: channel = ntv*16+lr, token packed 32h0+16mm+4lq+r
            #pragma unroll
            for (int k = 0; k < 6; ++k)
                #pragma unroll
                for (int mm = 0; mm < 2; ++mm)
                    acc[mm] = __builtin_amdgcn_mfma_f32_16x16x32_bf16(afrag[mm][k], bfrag[k], acc[mm], 0, 0, 0);
            const int cc   = ntv * 16 + lr;
            const float bb = b_qkv[384 + cc];
            #pragma unroll
            for (int mm = 0; mm < 2; ++mm) {
                bf16x4 v4;
                #pragma unroll
                for (int r = 0; r < 4; ++r) v4[r] = (bf16)(acc[mm][r] + bb);
                *(bf16x4*)&VTs[cc * VSTR + 32 * h0 + 16 * mm + 4 * lq] = v4;
            }
        }

        // select our Q row-tile's X-frags with STATIC indexing (no runtime array index)
        bf16x8 aq[6];
        #pragma unroll
        for (int k = 0; k < 6; ++k) aq[k] = mm_sel ? afrag[1][k] : afrag[0][k];

        // Q on the fly: rows 16*m2, channels hg*96..+95 (tiles qt = hg*6+u) -- fully unrolled
        unsigned pkq[6][2];
        #pragma unroll
        for (int u = 0; u < 6; ++u) {
            const int qt = hg * 6 + u;
            const bf16* wp = wqkvT + (size_t)(qt * 16 + lr) * CDIM + lq * 8;
            bf16x8 bfrag[6];
            #pragma unroll
            for (int k = 0; k < 6; ++k) bfrag[k] = *(const bf16x8*)(wp + k * 32);
            f32x4 acc = f32x4{0.f, 0.f, 0.f, 0.f};
            #pragma unroll
            for (int k = 0; k < 6; ++k)
                acc = __builtin_amdgcn_mfma_f32_16x16x32_bf16(bfrag[k], aq[k], acc, 0, 0, 0);
            const f32x4 bq4 = *(const f32x4*)&b_qkv[qt * 16 + 4 * lq];
            pkq[u][0] = pack2bf(acc[0] + bq4[0], acc[1] + bq4[1]);
            pkq[u][1] = pack2bf(acc[2] + bq4[2], acc[3] + bq4[3]);
        }
        // D-layout -> B-frag conversion (verified machinery)
        const int src0 = lr + 32 * (lq & 1);
        u32x4 w0, w1, w2;
        #pragma unroll
        for (int w = 0; w < 4; ++w) {
            int srcl = src0 + 16 * (w >> 1);
            int s = w & 1;
            unsigned a0 = (unsigned)__shfl((int)pkq[0][s], srcl);
            unsigned b0 = (unsigned)__shfl((int)pkq[1][s], srcl);
            unsigned a1 = (unsigned)__shfl((int)pkq[2][s], srcl);
            unsigned b1 = (unsigned)__shfl((int)pkq[3][s], srcl);
            unsigned a2 = (unsigned)__shfl((int)pkq[4][s], srcl);
            unsigned b2 = (unsigned)__shfl((int)pkq[5][s], srcl);
            w0[w] = (lq & 2) ? b0 : a0;
            w1[w] = (lq & 2) ? b1 : a1;
            w2[w] = (lq & 2) ? b2 : a2;
        }
        qf[0] = __builtin_bit_cast(bf16x8, w0);
        qf[1] = __builtin_bit_cast(bf16x8, w1);
        qf[2] = __builtin_bit_cast(bf16x8, w2);
    }
    __syncthreads();   // K fully written

    // ---- phase 2: head-at-a-time attention; one barrier/head between QK^T(h) and O-write(h) ----
    {
        const int cls = ((wy == 7) ? 2 : 0) | ((wx == 7) ? 1 : 0);
        const bf16* bgp = biasG + (((size_t)cls * 6 + hg * 3) * 64 + (16 * m2 + lr)) * 64 + 4 * lq;
        const int src0 = lr + 32 * (lq & 1);
        const float SC = SCALE * LOG2E;

        #pragma unroll
        for (int hh = 0; hh < 3; ++hh) {
            const int h = hg * 3 + hh;
            // QK^T(h): reads K cols h*32..+31 (untouched by prior O-writes)
            f32x4 st[4];
            #pragma unroll
            for (int n = 0; n < 4; ++n) {
                bf16x8 ak = *(const bf16x8*)&BufA[(16 * n + lr) * XSTR + h * 32 + lq * 8];
                st[n] = __builtin_amdgcn_mfma_f32_16x16x32_bf16(ak, qf[hh], f32x4{0.f, 0.f, 0.f, 0.f}, 0, 0, 0);
            }
            bf16x4 b4[4];
            #pragma unroll
            for (int n = 0; n < 4; ++n) b4[n] = *(const bf16x4*)(bgp + hh * 4096 + 16 * n);
            __syncthreads();   // all QK^T(h) reads done -> K[h] columns reusable for O

            float p[4][4];
            float umax = -1e30f;
            #pragma unroll
            for (int n = 0; n < 4; ++n)
                #pragma unroll
                for (int r = 0; r < 4; ++r) {
                    float v = fmaf(st[n][r], SC, (float)b4[n][r]);
                    p[n][r] = v;
                    umax = fmaxf(umax, v);
                }
            umax = fmaxf(umax, __shfl_xor(umax, 16));
            umax = fmaxf(umax, __shfl_xor(umax, 32));
            float sum = 0.f;
            #pragma unroll
            for (int n = 0; n < 4; ++n)
                #pragma unroll
                for (int r = 0; r < 4; ++r) {
                    float e = exp2f(p[n][r] - umax);
                    p[n][r] = e; sum += e;
                }
            sum += __shfl_xor(sum, 16);
            sum += __shfl_xor(sum, 32);
            const float inv = 1.f / sum;
            unsigned pk[4][2];
            #pragma unroll
            for (int n = 0; n < 4; ++n)
                #pragma unroll
                for (int s = 0; s < 2; ++s)
                    pk[n][s] = pack2bf(p[n][2 * s] * inv, p[n][2 * s + 1] * inv);
            u32x4 ptw0, ptw1;
            #pragma unroll
            for (int w = 0; w < 4; ++w) {
                int srcl = src0 + 16 * (w >> 1);
                int s = w & 1;
                unsigned a0 = (unsigned)__shfl((int)pk[0][s], srcl);
                unsigned b0 = (unsigned)__shfl((int)pk[1][s], srcl);
                unsigned a1 = (unsigned)__shfl((int)pk[2][s], srcl);
                unsigned b1 = (unsigned)__shfl((int)pk[3][s], srcl);
                ptw0[w] = (lq & 2) ? b0 : a0;
                ptw1[w] = (lq & 2) ? b1 : a1;
            }
            bf16x8 bp0 = __builtin_bit_cast(bf16x8, ptw0);
            bf16x8 bp1 = __builtin_bit_cast(bf16x8, ptw1);
            // PV: O^T = V^T · P^T
            f32x4 ot[2];
            #pragma unroll
            for (int dt = 0; dt < 2; ++dt) {
                const bf16* vrow = &VTs[(h * 32 + 16 * dt + lr) * VSTR + lq * 8];
                bf16x8 av0 = *(const bf16x8*)(vrow);
                bf16x8 av1 = *(const bf16x8*)(vrow + 32);
                ot[dt] = __builtin_amdgcn_mfma_f32_16x16x32_bf16(av0, bp0, f32x4{0.f, 0.f, 0.f, 0.f}, 0, 0, 0);
                ot[dt] = __builtin_amdgcn_mfma_f32_16x16x32_bf16(av1, bp1, ot[dt], 0, 0, 0);
            }
            // O^T[d][i] -> BufA[i][h*32+d] (over K[h]; wave-private (m2,h) region)
            #pragma unroll
            for (int dt = 0; dt < 2; ++dt) {
                bf16x4 o4;
                #pragma unroll
                for (int r = 0; r < 4; ++r) o4[r] = (bf16)ot[dt][r];
                *(bf16x4*)&BufA[(16 * m2 + lr) * XSTR + h * 32 + 16 * dt + 4 * lq] = o4;
            }
        }
    }
    __syncthreads();

    // ---- phase 3: proj + bias, swapped, dual-acc; wave = (half = w&1, cg3 = w>>1), 3 units ----
    {
        const int half = wave & 1;
        const int cg3  = wave >> 1;
        bf16x8 ofrag[2][6];
        #pragma unroll
        for (int mm = 0; mm < 2; ++mm)
            #pragma unroll
            for (int k = 0; k < 6; ++k)
                ofrag[mm][k] = *(const bf16x8*)&BufA[(32 * half + 16 * mm + lr) * XSTR + k * 32 + lq * 8];
        float* orow[2];
        bool   valid[2];
        #pragma unroll
        for (int mm = 0; mm < 2; ++mm) {
            const int row = 32 * half + 16 * mm + lr;
            valid[mm] = row < NTOK;
            int rr = valid[mm] ? row : 0;
            int ty = rr / 7, tx = rr % 7;
            int oy = wy * 7 + ty + SHIFTV; if (oy >= IMG) oy -= IMG;
            int ox = wx * 7 + tx + SHIFTV; if (ox >= IMG) ox -= IMG;
            orow[mm] = out + (((size_t)bimg * IMG + oy) * IMG + ox) * CDIM;
        }

        #pragma unroll
        for (int s3 = 0; s3 < 3; ++s3) {
            const int nt = cg3 + 4 * s3;
            const bf16* wp = wprojT + (size_t)(nt * 16 + lr) * CDIM + lq * 8;
            bf16x8 wfrag[6];
            #pragma unroll
            for (int k = 0; k < 6; ++k) wfrag[k] = *(const bf16x8*)(wp + k * 32);
            f32x4 acc[2];
            acc[0] = f32x4{0.f, 0.f, 0.f, 0.f}; acc[1] = f32x4{0.f, 0.f, 0.f, 0.f};
            #pragma unroll
            for (int k = 0; k < 6; ++k)
                #pragma unroll
                for (int mm = 0; mm < 2; ++mm)
                    acc[mm] = __builtin_amdgcn_mfma_f32_16x16x32_bf16(wfrag[k], ofrag[mm][k], acc[mm], 0, 0, 0);
            const int c0 = nt * 16 + 4 * lq;
            const f32x4 bp = *(const f32x4*)&b_proj[c0];
            #pragma unroll
            for (int mm = 0; mm < 2; ++mm) {
                if (valid[mm]) {
                    f32x4 v;
                    #pragma unroll
                    for (int r = 0; r < 4; ++r) v[r] = acc[mm][r] + bp[r];
                    *(f32x4*)&orow[mm][c0] = v;
                }
            }
        }
    }
}

extern "C" void kernel_launch(void* const* d_in, const int* in_sizes, int n_in,
                              void* d_out, int out_size, void* d_ws, size_t ws_size,
                              hipStream_t stream) {
    const float* x           = (const float*)d_in[0];
    const float* gamma       = (const float*)d_in[1];
    const float* beta        = (const float*)d_in[2];
    const float* w_qkv       = (const float*)d_in[3];
    const float* b_qkv       = (const float*)d_in[4];
    const float* rel_table   = (const float*)d_in[5];
    const float* w_proj      = (const float*)d_in[6];
    const float* b_proj      = (const float*)d_in[7];
    // d_in[8] = mask_matrix: folded into biasG table
    float* out = (float*)d_out;

    bf16* wqkvT  = (bf16*)d_ws;                                    // 221184 B
    bf16* wprojT = (bf16*)((char*)d_ws + 221184);                  //  73728 B
    bf16* biasG  = (bf16*)((char*)d_ws + 221184 + 73728);          // 196608 B

    prep_weights<<<432, 256, 0, stream>>>(w_qkv, w_proj, rel_table, wqkvT, wprojT, biasG);
    swin_block<<<4096, 512, 0, stream>>>(x, gamma, beta, wqkvT, b_qkv, biasG,
                                         wprojT, b_proj, out);
}